// Round 4
// baseline (988.438 us; speedup 1.0000x reference)
//
#include <hip/hip_runtime.h>
#include <hip/hip_cooperative_groups.h>
#include <cmath>

namespace cg = cooperative_groups;

#define NTOK 3072
#define NBLK 3
#define NTHR 256
#define GRID_MAX 768

__device__ __forceinline__ float sig(float v) { return 1.0f / (1.0f + expf(-v)); }

struct Params {
    const float *ql, *cl, *plm;
    const float *ada_g_w, *ada_g_b, *ada_b_w;
    const float *wq, *bq, *wk, *wv;
    const float *z_ln_g, *z_ln_b, *wz;
    const float *wg, *wo, *sg_w, *sg_b;
    const float *ada2_g_w, *ada2_g_b, *ada2_b_w;
    const float *ff1, *ff2, *ff3, *sg2_w, *sg2_b;
    float *s_ln, *x, *ybuf, *attn, *qkvg, *ffb, *anew, *zb;
    float *out;
};

// ---- stage 32 rows x 128 cols into LDS ----
__device__ __forceinline__ void stage32(const float* __restrict__ A, int row0,
                                        float* __restrict__ As, int tid)
{
#pragma unroll
    for (int it = 0; it < 4; it++) {
        int fo = (tid + it * 256) * 4;
        int r = fo >> 7, c = fo & 127;
        *(float4*)&As[r * 128 + c] = *(const float4*)&A[(size_t)(row0 + r) * 128 + c];
    }
}
// ---- stage 32 rows x 128-col slice of a 256-wide matrix ----
__device__ __forceinline__ void stage32s(const float* __restrict__ A, int row0, int coff,
                                         float* __restrict__ As, int tid)
{
#pragma unroll
    for (int it = 0; it < 4; it++) {
        int fo = (tid + it * 256) * 4;
        int r = fo >> 7, c = fo & 127;
        *(float4*)&As[r * 128 + c] = *(const float4*)&A[(size_t)(row0 + r) * 256 + coff + c];
    }
}

// ================= init: LN(cl) -> s_ln, pair bias zb =================
__device__ void phase_init(const Params& P, int bid, int nwg, int tid, float* sm)
{
    // wzg at sm[0..191] ([i*16+c]*4+h), zb0 at sm[192..203]
    if (tid < 192) {
        int i = tid >> 6, rem = tid & 63, c = rem >> 2, h = rem & 3;
        sm[(i * 16 + c) * 4 + h] = P.z_ln_g[i * 16 + c] * P.wz[(i * 16 + c) * 4 + h];
    }
    if (tid < 12) {
        int i = tid >> 2, h = tid & 3;
        float s = 0.0f;
        for (int c = 0; c < 16; c++) s += P.z_ln_b[i * 16 + c] * P.wz[(i * 16 + c) * 4 + h];
        sm[192 + tid] = s;
    }
    __syncthreads();
    int lane = tid & 63, wid = tid >> 6;
    for (int r = bid * 4 + wid; r < NTOK; r += nwg * 4) {
        const float* s = P.cl + (size_t)r * 128;
        float x0 = s[lane], x1 = s[lane + 64];
        float sum = x0 + x1;
#pragma unroll
        for (int m = 1; m < 64; m <<= 1) sum += __shfl_xor(sum, m);
        float mean = sum * (1.0f / 128.0f);
        float d0 = x0 - mean, d1 = x1 - mean;
        float v = d0 * d0 + d1 * d1;
#pragma unroll
        for (int m = 1; m < 64; m <<= 1) v += __shfl_xor(v, m);
        float rs = 1.0f / sqrtf(v * (1.0f / 128.0f) + 1e-5f);
        float* d = P.s_ln + (size_t)r * 128;
        d[lane] = d0 * rs;
        d[lane + 64] = d1 * rs;
    }
    for (int p = bid * NTHR + tid; p < 96 * 32 * 128; p += nwg * NTHR) {
        int j = p >> 12;
        int rem = p & 4095;
        int qi = rem >> 7, kk = rem & 127;
        int kstart = max(0, j * 32 - 48);
        int W = min(NTOK, j * 32 + 80) - kstart;
        if (kk >= W) continue;
        int q = j * 32 + qi;
        const float* src = P.plm + ((size_t)q * NTOK + (size_t)(kstart + kk)) * 16;
        float xv[16];
        *(float4*)(xv + 0)  = *(const float4*)(src + 0);
        *(float4*)(xv + 4)  = *(const float4*)(src + 4);
        *(float4*)(xv + 8)  = *(const float4*)(src + 8);
        *(float4*)(xv + 12) = *(const float4*)(src + 12);
        float s = 0.0f;
#pragma unroll
        for (int c = 0; c < 16; c++) s += xv[c];
        float mean = s * (1.0f / 16.0f);
        float var = 0.0f;
#pragma unroll
        for (int c = 0; c < 16; c++) { float d = xv[c] - mean; var += d * d; }
        float rs = 1.0f / sqrtf(var * (1.0f / 16.0f) + 1e-5f);
#pragma unroll
        for (int c = 0; c < 16; c++) xv[c] = (xv[c] - mean) * rs;
#pragma unroll
        for (int i = 0; i < NBLK; i++) {
            float o0 = sm[192 + i * 4 + 0], o1 = sm[192 + i * 4 + 1];
            float o2 = sm[192 + i * 4 + 2], o3 = sm[192 + i * 4 + 3];
#pragma unroll
            for (int c = 0; c < 16; c++) {
                float v = xv[c];
                float4 w4 = *(const float4*)&sm[(i * 16 + c) * 4];
                o0 = fmaf(v, w4.x, o0);
                o1 = fmaf(v, w4.y, o1);
                o2 = fmaf(v, w4.z, o2);
                o3 = fmaf(v, w4.w, o3);
            }
            size_t base = (((size_t)(i * 4)) * NTOK + q) * 128 + kk;
            P.zb[base]                      = o0;
            P.zb[base + (size_t)NTOK * 128] = o1;
            P.zb[base + (size_t)NTOK * 256] = o2;
            P.zb[base + (size_t)NTOK * 384] = o3;
        }
    }
}

// ================= p1a: x,y adaLN (384 tasks: 96 rg x {x,y} x 2 colchunks) =================
__device__ void phase_p1a(const Params& P, int i, int bid, int nwg, int tid, float* sm)
{
    const float* aprev = (i == 0) ? P.ql : P.anew;
    const float* adag  = P.ada_g_w  + (size_t)i * 16384;
    const float* adab  = P.ada_b_w  + (size_t)i * 16384;
    const float* ada2g = P.ada2_g_w + (size_t)i * 16384;
    const float* ada2b = P.ada2_b_w + (size_t)i * 16384;
    int lane = tid & 63, wid = tid >> 6;
    int cl2 = (lane & 31) * 2, half = lane >> 5;
    int r0 = (wid * 2 + half) * 4;
    for (int t = bid; t < 384; t += nwg) {
        int rg = t >> 2, sub = t & 3;
        int which = sub >> 1, cc = sub & 1;
        int row0 = rg * 32, cbase = cc * 64;
        int c = cbase + cl2;
        __syncthreads();
        stage32(aprev, row0, sm, tid);
        __syncthreads();
        // LN rows in place (wave wid owns rows wid*8..wid*8+7)
        for (int rr = 0; rr < 8; rr++) {
            int r = wid * 8 + rr;
            float x0 = sm[r * 128 + lane], x1 = sm[r * 128 + lane + 64];
            float sum = x0 + x1;
#pragma unroll
            for (int m = 1; m < 64; m <<= 1) sum += __shfl_xor(sum, m);
            float mean = sum * (1.0f / 128.0f);
            float d0 = x0 - mean, d1 = x1 - mean;
            float v = d0 * d0 + d1 * d1;
#pragma unroll
            for (int m = 1; m < 64; m <<= 1) v += __shfl_xor(v, m);
            float rs = 1.0f / sqrtf(v * (1.0f / 128.0f) + 1e-5f);
            sm[r * 128 + lane] = d0 * rs;
            sm[r * 128 + lane + 64] = d1 * rs;
        }
        __syncthreads();
        float lnv[4][2];
#pragma unroll
        for (int rr = 0; rr < 4; rr++) {
            lnv[rr][0] = sm[(r0 + rr) * 128 + c];
            lnv[rr][1] = sm[(r0 + rr) * 128 + c + 1];
        }
        __syncthreads();
        stage32(P.s_ln, row0, sm, tid);
        __syncthreads();
        const float* Wg = which ? ada2g : adag;
        const float* Wb = which ? ada2b : adab;
        const float* bg = which ? (P.ada2_g_b + (size_t)i * 128) : (P.ada_g_b + (size_t)i * 128);
        float accg[4][2] = {}, accb[4][2] = {};
        for (int k = 0; k < 128; k += 4) {
            float2 g0 = *(const float2*)&Wg[(size_t)(k + 0) * 128 + c];
            float2 g1 = *(const float2*)&Wg[(size_t)(k + 1) * 128 + c];
            float2 g2 = *(const float2*)&Wg[(size_t)(k + 2) * 128 + c];
            float2 g3 = *(const float2*)&Wg[(size_t)(k + 3) * 128 + c];
            float2 b0 = *(const float2*)&Wb[(size_t)(k + 0) * 128 + c];
            float2 b1 = *(const float2*)&Wb[(size_t)(k + 1) * 128 + c];
            float2 b2 = *(const float2*)&Wb[(size_t)(k + 2) * 128 + c];
            float2 b3 = *(const float2*)&Wb[(size_t)(k + 3) * 128 + c];
#pragma unroll
            for (int rr = 0; rr < 4; rr++) {
                float4 a = *(const float4*)&sm[(r0 + rr) * 128 + k];
                accg[rr][0] = fmaf(a.x, g0.x, fmaf(a.y, g1.x, fmaf(a.z, g2.x, fmaf(a.w, g3.x, accg[rr][0]))));
                accg[rr][1] = fmaf(a.x, g0.y, fmaf(a.y, g1.y, fmaf(a.z, g2.y, fmaf(a.w, g3.y, accg[rr][1]))));
                accb[rr][0] = fmaf(a.x, b0.x, fmaf(a.y, b1.x, fmaf(a.z, b2.x, fmaf(a.w, b3.x, accb[rr][0]))));
                accb[rr][1] = fmaf(a.x, b0.y, fmaf(a.y, b1.y, fmaf(a.z, b2.y, fmaf(a.w, b3.y, accb[rr][1]))));
            }
        }
        float* outp = which ? P.ybuf : P.x;
        float2 bgv = *(const float2*)&bg[c];
#pragma unroll
        for (int rr = 0; rr < 4; rr++) {
            int r = row0 + r0 + rr;
            float2 o;
            o.x = sig(accg[rr][0] + bgv.x) * lnv[rr][0] + accb[rr][0];
            o.y = sig(accg[rr][1] + bgv.y) * lnv[rr][1] + accb[rr][1];
            *(float2*)&outp[(size_t)r * 128 + c] = o;
        }
    }
}

// ================= p1b: qkvg + ff (576 tasks: 96 rg x {q,k,v,g,ff0,ff1}) =================
__device__ void phase_p1b(const Params& P, int i, int bid, int nwg, int tid, float* sm)
{
    const float* wq_i = P.wq  + (size_t)i * 16384;
    const float* wk_i = P.wk  + (size_t)i * 16384;
    const float* wv_i = P.wv  + (size_t)i * 16384;
    const float* wg_i = P.wg  + (size_t)i * 16384;
    const float* bq_i = P.bq  + (size_t)i * 128;
    const float* ff1_i = P.ff1 + (size_t)i * 32768;
    const float* ff2_i = P.ff2 + (size_t)i * 32768;
    int lane = tid & 63, wid = tid >> 6;
    int c0 = lane * 2, r0 = wid * 8;
    for (int t = bid; t < 576; t += nwg) {
        int rg = t / 6, u = t % 6;
        int row0 = rg * 32;
        __syncthreads();
        stage32(u < 4 ? P.x : P.ybuf, row0, sm, tid);
        __syncthreads();
        if (u < 4) {
            const float* Wm = (u == 0) ? wq_i : (u == 1) ? wk_i : (u == 2) ? wv_i : wg_i;
            float acc[8][2] = {};
            for (int k = 0; k < 128; k += 4) {
                float2 w0 = *(const float2*)&Wm[(size_t)(k + 0) * 128 + c0];
                float2 w1 = *(const float2*)&Wm[(size_t)(k + 1) * 128 + c0];
                float2 w2 = *(const float2*)&Wm[(size_t)(k + 2) * 128 + c0];
                float2 w3 = *(const float2*)&Wm[(size_t)(k + 3) * 128 + c0];
#pragma unroll
                for (int rr = 0; rr < 8; rr++) {
                    float4 a = *(const float4*)&sm[(r0 + rr) * 128 + k];
                    acc[rr][0] = fmaf(a.x, w0.x, fmaf(a.y, w1.x, fmaf(a.z, w2.x, fmaf(a.w, w3.x, acc[rr][0]))));
                    acc[rr][1] = fmaf(a.x, w0.y, fmaf(a.y, w1.y, fmaf(a.z, w2.y, fmaf(a.w, w3.y, acc[rr][1]))));
                }
            }
            float b0 = (u == 0) ? bq_i[c0] : 0.0f;
            float b1 = (u == 0) ? bq_i[c0 + 1] : 0.0f;
#pragma unroll
            for (int rr = 0; rr < 8; rr++) {
                int r = row0 + r0 + rr;
                *(float2*)&P.qkvg[(size_t)r * 512 + u * 128 + c0] =
                    make_float2(acc[rr][0] + b0, acc[rr][1] + b1);
            }
        } else {
            int ch = (u - 4) * 128;
            float acc1[8][2] = {}, acc2[8][2] = {};
            for (int k = 0; k < 128; k += 4) {
                float2 p0 = *(const float2*)&ff1_i[(size_t)(k + 0) * 256 + ch + c0];
                float2 p1 = *(const float2*)&ff1_i[(size_t)(k + 1) * 256 + ch + c0];
                float2 p2 = *(const float2*)&ff1_i[(size_t)(k + 2) * 256 + ch + c0];
                float2 p3 = *(const float2*)&ff1_i[(size_t)(k + 3) * 256 + ch + c0];
                float2 q0 = *(const float2*)&ff2_i[(size_t)(k + 0) * 256 + ch + c0];
                float2 q1 = *(const float2*)&ff2_i[(size_t)(k + 1) * 256 + ch + c0];
                float2 q2 = *(const float2*)&ff2_i[(size_t)(k + 2) * 256 + ch + c0];
                float2 q3 = *(const float2*)&ff2_i[(size_t)(k + 3) * 256 + ch + c0];
#pragma unroll
                for (int rr = 0; rr < 8; rr++) {
                    float4 a = *(const float4*)&sm[(r0 + rr) * 128 + k];
                    acc1[rr][0] = fmaf(a.x, p0.x, fmaf(a.y, p1.x, fmaf(a.z, p2.x, fmaf(a.w, p3.x, acc1[rr][0]))));
                    acc1[rr][1] = fmaf(a.x, p0.y, fmaf(a.y, p1.y, fmaf(a.z, p2.y, fmaf(a.w, p3.y, acc1[rr][1]))));
                    acc2[rr][0] = fmaf(a.x, q0.x, fmaf(a.y, q1.x, fmaf(a.z, q2.x, fmaf(a.w, q3.x, acc2[rr][0]))));
                    acc2[rr][1] = fmaf(a.x, q0.y, fmaf(a.y, q1.y, fmaf(a.z, q2.y, fmaf(a.w, q3.y, acc2[rr][1]))));
                }
            }
#pragma unroll
            for (int rr = 0; rr < 8; rr++) {
                int r = row0 + r0 + rr;
                float2 o;
                o.x = acc1[rr][0] * sig(acc1[rr][0]) * acc2[rr][0];
                o.y = acc1[rr][1] * sig(acc1[rr][1]) * acc2[rr][1];
                *(float2*)&P.ffb[(size_t)r * 256 + ch + c0] = o;
            }
        }
    }
}

// ================= attn: 768 tasks (96 j x 4 h x 2 q-halves), K/V from cache =================
__device__ void phase_attn(const Params& P, int i, int bid, int nwg, int tid, float* sm)
{
    const float scale = 0.17677669529663687f;
    for (int t = bid; t < 768; t += nwg) {
        int j = t >> 3, sub = t & 7, h = sub >> 1, qh = sub & 1;
        int q0 = j * 32 + qh * 16;
        int kstart = max(0, j * 32 - 48);
        int W = min(NTOK, j * 32 + 80) - kstart;
        __syncthreads();
        int qi = tid & 15, kg = tid >> 4;
        float qreg[32];
        {
            const float* qp = &P.qkvg[(size_t)(q0 + qi) * 512 + h * 32];
#pragma unroll
            for (int d4 = 0; d4 < 8; d4++) {
                float4 tq = *(const float4*)(qp + d4 * 4);
                qreg[d4 * 4] = tq.x; qreg[d4 * 4 + 1] = tq.y;
                qreg[d4 * 4 + 2] = tq.z; qreg[d4 * 4 + 3] = tq.w;
            }
        }
        const float* zrow = &P.zb[((size_t)(i * 4 + h) * NTOK + q0 + qi) * 128];
#pragma unroll
        for (int t2 = 0; t2 < 8; t2++) {
            int kk = kg + t2 * 16;
            if (kk < W) {
                const float* kp = &P.qkvg[(size_t)(kstart + kk) * 512 + 128 + h * 32];
                float acc = 0.0f;
#pragma unroll
                for (int d4 = 0; d4 < 8; d4++) {
                    float4 kv = *(const float4*)(kp + d4 * 4);
                    acc = fmaf(qreg[d4 * 4 + 0], kv.x, acc);
                    acc = fmaf(qreg[d4 * 4 + 1], kv.y, acc);
                    acc = fmaf(qreg[d4 * 4 + 2], kv.z, acc);
                    acc = fmaf(qreg[d4 * 4 + 3], kv.w, acc);
                }
                sm[qi * 129 + kk] = fmaf(acc, scale, zrow[kk]);
            }
        }
        __syncthreads();
        {
            int row = tid >> 4, s2 = tid & 15;
            float m = -3.0e38f;
            for (int kk = s2; kk < W; kk += 16) m = fmaxf(m, sm[row * 129 + kk]);
#pragma unroll
            for (int mm = 1; mm < 16; mm <<= 1) m = fmaxf(m, __shfl_xor(m, mm));
            float ssum = 0.0f;
            for (int kk = s2; kk < W; kk += 16) {
                float e = expf(sm[row * 129 + kk] - m);
                sm[row * 129 + kk] = e; ssum += e;
            }
#pragma unroll
            for (int mm = 1; mm < 16; mm <<= 1) ssum += __shfl_xor(ssum, mm);
            float rinv = 1.0f / ssum;
            for (int kk = s2; kk < W; kk += 16) sm[row * 129 + kk] *= rinv;
        }
        __syncthreads();
        {
            int qi2 = tid & 15, dg = tid >> 4;
            int d0 = dg * 2;
            float o0 = 0.0f, o1 = 0.0f, o0b = 0.0f, o1b = 0.0f;
            const float* vbase = &P.qkvg[(size_t)kstart * 512 + 256 + h * 32 + d0];
            for (int kk = 0; kk < W; kk += 2) {
                float p0 = sm[qi2 * 129 + kk], p1 = sm[qi2 * 129 + kk + 1];
                float2 va = *(const float2*)(vbase + (size_t)kk * 512);
                float2 vb = *(const float2*)(vbase + (size_t)(kk + 1) * 512);
                o0  = fmaf(p0, va.x, o0);  o1  = fmaf(p0, va.y, o1);
                o0b = fmaf(p1, vb.x, o0b); o1b = fmaf(p1, vb.y, o1b);
            }
            o0 += o0b; o1 += o1b;
            float2 g2 = *(const float2*)&P.qkvg[(size_t)(q0 + qi2) * 512 + 384 + h * 32 + d0];
            *(float2*)&P.attn[(size_t)(q0 + qi2) * 128 + h * 32 + d0] =
                make_float2(o0 * sig(g2.x), o1 * sig(g2.y));
        }
    }
}

// ================= p3: bout + final (384 tasks: 96 rg x 4 colchunks of 32) =================
__device__ void phase_p3(const Params& P, int i, int bid, int nwg, int tid, float* sm)
{
    const float* sgw  = P.sg_w  + (size_t)i * 16384;
    const float* sgb  = P.sg_b  + (size_t)i * 128;
    const float* wo_i = P.wo    + (size_t)i * 16384;
    const float* sg2w = P.sg2_w + (size_t)i * 16384;
    const float* sg2b = P.sg2_b + (size_t)i * 128;
    const float* ff3_i = P.ff3  + (size_t)i * 32768;
    float* outp = (i == NBLK - 1) ? P.out : P.anew;
    int lane = tid & 63, wid = tid >> 6;
    int cl2 = (lane & 15) * 2, grp = lane >> 4;
    int r0 = (wid * 4 + grp) * 2;
    for (int t = bid; t < 384; t += nwg) {
        int rg = t >> 2, cc = t & 3;
        int row0 = rg * 32, c = cc * 32 + cl2;
        __syncthreads();
        stage32(P.s_ln, row0, sm, tid);
        __syncthreads();
        float asg[2][2] = {}, asg2[2][2] = {};
        for (int k = 0; k < 128; k += 4) {
            float2 u0 = *(const float2*)&sgw[(size_t)(k + 0) * 128 + c];
            float2 u1 = *(const float2*)&sgw[(size_t)(k + 1) * 128 + c];
            float2 u2 = *(const float2*)&sgw[(size_t)(k + 2) * 128 + c];
            float2 u3 = *(const float2*)&sgw[(size_t)(k + 3) * 128 + c];
            float2 v0 = *(const float2*)&sg2w[(size_t)(k + 0) * 128 + c];
            float2 v1 = *(const float2*)&sg2w[(size_t)(k + 1) * 128 + c];
            float2 v2 = *(const float2*)&sg2w[(size_t)(k + 2) * 128 + c];
            float2 v3 = *(const float2*)&sg2w[(size_t)(k + 3) * 128 + c];
#pragma unroll
            for (int rr = 0; rr < 2; rr++) {
                float4 a = *(const float4*)&sm[(r0 + rr) * 128 + k];
                asg[rr][0]  = fmaf(a.x, u0.x, fmaf(a.y, u1.x, fmaf(a.z, u2.x, fmaf(a.w, u3.x, asg[rr][0]))));
                asg[rr][1]  = fmaf(a.x, u0.y, fmaf(a.y, u1.y, fmaf(a.z, u2.y, fmaf(a.w, u3.y, asg[rr][1]))));
                asg2[rr][0] = fmaf(a.x, v0.x, fmaf(a.y, v1.x, fmaf(a.z, v2.x, fmaf(a.w, v3.x, asg2[rr][0]))));
                asg2[rr][1] = fmaf(a.x, v0.y, fmaf(a.y, v1.y, fmaf(a.z, v2.y, fmaf(a.w, v3.y, asg2[rr][1]))));
            }
        }
        __syncthreads();
        stage32(P.attn, row0, sm, tid);
        __syncthreads();
        float awo[2][2] = {};
        for (int k = 0; k < 128; k += 4) {
            float2 w0 = *(const float2*)&wo_i[(size_t)(k + 0) * 128 + c];
            float2 w1 = *(const float2*)&wo_i[(size_t)(k + 1) * 128 + c];
            float2 w2 = *(const float2*)&wo_i[(size_t)(k + 2) * 128 + c];
            float2 w3 = *(const float2*)&wo_i[(size_t)(k + 3) * 128 + c];
#pragma unroll
            for (int rr = 0; rr < 2; rr++) {
                float4 a = *(const float4*)&sm[(r0 + rr) * 128 + k];
                awo[rr][0] = fmaf(a.x, w0.x, fmaf(a.y, w1.x, fmaf(a.z, w2.x, fmaf(a.w, w3.x, awo[rr][0]))));
                awo[rr][1] = fmaf(a.x, w0.y, fmaf(a.y, w1.y, fmaf(a.z, w2.y, fmaf(a.w, w3.y, awo[rr][1]))));
            }
        }
        float at[2][2] = {};
#pragma unroll
        for (int hh = 0; hh < 2; hh++) {
            __syncthreads();
            stage32s(P.ffb, row0, hh * 128, sm, tid);
            __syncthreads();
            const float* W3 = ff3_i + (size_t)hh * 128 * 128;
            for (int k = 0; k < 128; k += 4) {
                float2 w0 = *(const float2*)&W3[(size_t)(k + 0) * 128 + c];
                float2 w1 = *(const float2*)&W3[(size_t)(k + 1) * 128 + c];
                float2 w2 = *(const float2*)&W3[(size_t)(k + 2) * 128 + c];
                float2 w3 = *(const float2*)&W3[(size_t)(k + 3) * 128 + c];
#pragma unroll
                for (int rr = 0; rr < 2; rr++) {
                    float4 a = *(const float4*)&sm[(r0 + rr) * 128 + k];
                    at[rr][0] = fmaf(a.x, w0.x, fmaf(a.y, w1.x, fmaf(a.z, w2.x, fmaf(a.w, w3.x, at[rr][0]))));
                    at[rr][1] = fmaf(a.x, w0.y, fmaf(a.y, w1.y, fmaf(a.z, w2.y, fmaf(a.w, w3.y, at[rr][1]))));
                }
            }
        }
        float2 bv  = *(const float2*)&sgb[c];
        float2 bv2 = *(const float2*)&sg2b[c];
#pragma unroll
        for (int rr = 0; rr < 2; rr++) {
            int r = row0 + r0 + rr;
            float2 o;
            o.x = sig(asg[rr][0] + bv.x) * awo[rr][0] + sig(asg2[rr][0] + bv2.x) * at[rr][0];
            o.y = sig(asg[rr][1] + bv.y) * awo[rr][1] + sig(asg2[rr][1] + bv2.y) * at[rr][1];
            *(float2*)&outp[(size_t)r * 128 + c] = o;
        }
    }
}

// ================= fused cooperative kernel =================
__global__ __launch_bounds__(NTHR, 3) void fused_kernel(Params P)
{
    cg::grid_group grid = cg::this_grid();
    __shared__ __align__(16) float sm[4096];
    int tid = threadIdx.x, bid = blockIdx.x, nwg = gridDim.x;
    phase_init(P, bid, nwg, tid, sm);
    grid.sync();
    for (int i = 0; i < NBLK; i++) {
        phase_p1a(P, i, bid, nwg, tid, sm);  grid.sync();
        phase_p1b(P, i, bid, nwg, tid, sm);  grid.sync();
        phase_attn(P, i, bid, nwg, tid, sm); grid.sync();
        phase_p3(P, i, bid, nwg, tid, sm);
        if (i < NBLK - 1) grid.sync();
    }
}

// ================= fallback per-phase kernels =================
__global__ __launch_bounds__(NTHR, 3) void k_init(Params P)
{ __shared__ __align__(16) float sm[4096]; phase_init(P, blockIdx.x, gridDim.x, threadIdx.x, sm); }
__global__ __launch_bounds__(NTHR, 3) void k_p1a(Params P, int i)
{ __shared__ __align__(16) float sm[4096]; phase_p1a(P, i, blockIdx.x, gridDim.x, threadIdx.x, sm); }
__global__ __launch_bounds__(NTHR, 3) void k_p1b(Params P, int i)
{ __shared__ __align__(16) float sm[4096]; phase_p1b(P, i, blockIdx.x, gridDim.x, threadIdx.x, sm); }
__global__ __launch_bounds__(NTHR, 3) void k_attn(Params P, int i)
{ __shared__ __align__(16) float sm[4096]; phase_attn(P, i, blockIdx.x, gridDim.x, threadIdx.x, sm); }
__global__ __launch_bounds__(NTHR, 3) void k_p3(Params P, int i)
{ __shared__ __align__(16) float sm[4096]; phase_p3(P, i, blockIdx.x, gridDim.x, threadIdx.x, sm); }

extern "C" void kernel_launch(void* const* d_in, const int* in_sizes, int n_in,
                              void* d_out, int out_size, void* d_ws, size_t ws_size,
                              hipStream_t stream)
{
    Params P;
    P.ql       = (const float*)d_in[0];
    P.cl       = (const float*)d_in[1];
    P.plm      = (const float*)d_in[2];
    P.ada_g_w  = (const float*)d_in[3];
    P.ada_g_b  = (const float*)d_in[4];
    P.ada_b_w  = (const float*)d_in[5];
    P.wq       = (const float*)d_in[6];
    P.bq       = (const float*)d_in[7];
    P.wk       = (const float*)d_in[8];
    P.wv       = (const float*)d_in[9];
    P.z_ln_g   = (const float*)d_in[10];
    P.z_ln_b   = (const float*)d_in[11];
    P.wz       = (const float*)d_in[12];
    P.wg       = (const float*)d_in[13];
    P.wo       = (const float*)d_in[14];
    P.sg_w     = (const float*)d_in[15];
    P.sg_b     = (const float*)d_in[16];
    P.ada2_g_w = (const float*)d_in[17];
    P.ada2_g_b = (const float*)d_in[18];
    P.ada2_b_w = (const float*)d_in[19];
    P.ff1      = (const float*)d_in[20];
    P.ff2      = (const float*)d_in[21];
    P.ff3      = (const float*)d_in[22];
    P.sg2_w    = (const float*)d_in[23];
    P.sg2_b    = (const float*)d_in[24];

    float* ws = (float*)d_ws;
    const size_t NC = (size_t)NTOK * 128;
    P.s_ln = ws;
    P.x    = ws + NC;
    P.ybuf = ws + 2 * NC;
    P.attn = ws + 3 * NC;
    P.anew = ws + 4 * NC;
    P.qkvg = ws + 5 * NC;   // N x 512
    P.ffb  = ws + 9 * NC;   // N x 256
    P.zb   = ws + 11 * NC;  // 3 x 4 x N x 128
    P.out  = (float*)d_out;

    int occ = 0;
    hipError_t oe = hipOccupancyMaxActiveBlocksPerMultiprocessor(&occ, fused_kernel, NTHR, 0);
    int grid = GRID_MAX;
    if (oe == hipSuccess && occ > 0) {
        int g = occ * 256;
        if (g < grid) grid = g;
    } else {
        grid = 256;
    }

    void* args[] = { &P };
    hipError_t e = hipLaunchCooperativeKernel((void*)fused_kernel, dim3(grid), dim3(NTHR),
                                              args, 0, stream);
    if (e != hipSuccess) {
        // fallback: plain per-phase launches (same device code, grid-stride)
        k_init<<<GRID_MAX, NTHR, 0, stream>>>(P);
        for (int i = 0; i < NBLK; i++) {
            k_p1a<<<GRID_MAX, NTHR, 0, stream>>>(P, i);
            k_p1b<<<GRID_MAX, NTHR, 0, stream>>>(P, i);
            k_attn<<<GRID_MAX, NTHR, 0, stream>>>(P, i);
            k_p3<<<GRID_MAX, NTHR, 0, stream>>>(P, i);
        }
    }
}

// Round 5
// 351.126 us; speedup vs baseline: 2.8150x; 2.8150x over previous
//
#include <hip/hip_runtime.h>
#include <cmath>

#define NTOK 3072
#define NBLK 3
#define PSS 133   // ps LDS stride: %32 == 5 (coprime) -> conflict-free PV reads

__device__ __forceinline__ float sig(float v) { return 1.0f / (1.0f + expf(-v)); }

struct Params {
    const float *ql, *cl, *plm;
    const float *ada_g_w, *ada_g_b, *ada_b_w;
    const float *wq, *bq, *wk, *wv;
    const float *z_ln_g, *z_ln_b, *wz;
    const float *wg, *wo, *sg_w, *sg_b;
    const float *ada2_g_w, *ada2_g_b, *ada2_b_w;
    const float *ff1, *ff2, *ff3, *sg2_w, *sg2_b;
    float *s_ln, *ln_a, *attn, *qkvg, *ffb, *zb;
    float *out;
};

// ================= k0: LN(cl)->s_ln, LN(ql)->ln_a, pair-bias zb =================
// grid 768: bid&7 -> XCD token range for zb locality
__global__ __launch_bounds__(256) void k0_init(Params P)
{
    __shared__ __align__(16) float wzg[204];  // [0..191]: (i*16+c)*4+h ; [192..203]: zb0
    int tid = threadIdx.x, bid = blockIdx.x;
    if (tid < 192) {
        int i = tid >> 6, rem = tid & 63, c = rem >> 2, h = rem & 3;
        wzg[(i * 16 + c) * 4 + h] = P.z_ln_g[i * 16 + c] * P.wz[(i * 16 + c) * 4 + h];
    }
    if (tid < 12) {
        int i = tid >> 2, h = tid & 3;
        float s = 0.0f;
        for (int c = 0; c < 16; c++) s += P.z_ln_b[i * 16 + c] * P.wz[(i * 16 + c) * 4 + h];
        wzg[192 + tid] = s;
    }
    __syncthreads();
    int lane = tid & 63, wid = tid >> 6;
    for (int r = bid * 4 + wid; r < 2 * NTOK; r += gridDim.x * 4) {
        const float* s = (r < NTOK) ? (P.cl + (size_t)r * 128) : (P.ql + (size_t)(r - NTOK) * 128);
        float* d       = (r < NTOK) ? (P.s_ln + (size_t)r * 128) : (P.ln_a + (size_t)(r - NTOK) * 128);
        float x0 = s[lane], x1 = s[lane + 64];
        float sum = x0 + x1;
#pragma unroll
        for (int m = 1; m < 64; m <<= 1) sum += __shfl_xor(sum, m);
        float mean = sum * (1.0f / 128.0f);
        float d0 = x0 - mean, d1 = x1 - mean;
        float v = d0 * d0 + d1 * d1;
#pragma unroll
        for (int m = 1; m < 64; m <<= 1) v += __shfl_xor(v, m);
        float rs = 1.0f / sqrtf(v * (1.0f / 128.0f) + 1e-5f);
        d[lane] = d0 * rs;
        d[lane + 64] = d1 * rs;
    }
    // zb: XCD-affine: x8 owns tokens [x8*384, x8*384+384)
    int x8 = bid & 7, g = bid >> 3;
    int jl = g % 12, qs = g / 12;           // 12 j per XCD, 8 q-subtiles of 4
    int j = x8 * 12 + jl;
    int kstart = max(0, j * 32 - 48);
    int W = min(NTOK, j * 32 + 80) - kstart;
    int q0 = j * 32 + qs * 4;
    for (int p = tid; p < 4 * 128; p += 256) {
        int qi = p >> 7, kk = p & 127;
        if (kk >= W) continue;
        int q = q0 + qi;
        const float* src = P.plm + ((size_t)q * NTOK + (size_t)(kstart + kk)) * 16;
        float xv[16];
        *(float4*)(xv + 0)  = *(const float4*)(src + 0);
        *(float4*)(xv + 4)  = *(const float4*)(src + 4);
        *(float4*)(xv + 8)  = *(const float4*)(src + 8);
        *(float4*)(xv + 12) = *(const float4*)(src + 12);
        float s = 0.0f;
#pragma unroll
        for (int c = 0; c < 16; c++) s += xv[c];
        float mean = s * (1.0f / 16.0f);
        float var = 0.0f;
#pragma unroll
        for (int c = 0; c < 16; c++) { float d = xv[c] - mean; var += d * d; }
        float rs = 1.0f / sqrtf(var * (1.0f / 16.0f) + 1e-5f);
#pragma unroll
        for (int c = 0; c < 16; c++) xv[c] = (xv[c] - mean) * rs;
#pragma unroll
        for (int i = 0; i < NBLK; i++) {
            float o0 = wzg[192 + i * 4 + 0], o1 = wzg[192 + i * 4 + 1];
            float o2 = wzg[192 + i * 4 + 2], o3 = wzg[192 + i * 4 + 3];
#pragma unroll
            for (int c = 0; c < 16; c++) {
                float v = xv[c];
                float4 w4 = *(const float4*)&wzg[(i * 16 + c) * 4];
                o0 = fmaf(v, w4.x, o0);
                o1 = fmaf(v, w4.y, o1);
                o2 = fmaf(v, w4.z, o2);
                o3 = fmaf(v, w4.w, o3);
            }
            size_t base = (((size_t)(i * 4)) * NTOK + q) * 128 + kk;
            P.zb[base]                      = o0;
            P.zb[base + (size_t)NTOK * 128] = o1;
            P.zb[base + (size_t)NTOK * 256] = o2;
            P.zb[base + (size_t)NTOK * 384] = o3;
        }
    }
}

// ================= k1: pre (x,y in-kernel; -> qkvg, ffb) =================
// grid 768 = 8 XCD x 24 tiles(16 rows) x 4 units {q+k, v+g, ff-lo, ff-hi}
__global__ __launch_bounds__(256) void k1_pre(Params P, int i)
{
    __shared__ __align__(16) float smA[16 * 132];
    __shared__ __align__(16) float smX[16 * 132];
    int tid = threadIdx.x, bid = blockIdx.x;
    int x8 = bid & 7, g = bid >> 3;
    int u = g / 24, tl = g % 24;
    int row0 = (x8 * 24 + tl) * 16;
    int lane = tid & 63, wid = tid >> 6;
    int cq = (lane & 31) * 4;
    int r0 = (wid * 2 + (lane >> 5)) * 2;
    // stage s_ln 16x128
#pragma unroll
    for (int it = 0; it < 2; it++) {
        int fo = (tid + it * 256) * 4;
        int r = fo >> 7, c = fo & 127;
        *(float4*)&smA[r * 132 + c] = *(const float4*)&P.s_ln[(size_t)(row0 + r) * 128 + c];
    }
    __syncthreads();
    // GEMM1: gate (adaG) + beta (adaB)
    const float* Wg = ((u < 2) ? P.ada_g_w : P.ada2_g_w) + (size_t)i * 16384 + cq;
    const float* Wb = ((u < 2) ? P.ada_b_w : P.ada2_b_w) + (size_t)i * 16384 + cq;
    const float* bg = ((u < 2) ? P.ada_g_b : P.ada2_g_b) + (size_t)i * 128;
    float g0[4] = {}, g1[4] = {}, b0[4] = {}, b1[4] = {};
#pragma unroll 4
    for (int k = 0; k < 128; k++) {
        float4 wg4 = *(const float4*)(Wg + (size_t)k * 128);
        float4 wb4 = *(const float4*)(Wb + (size_t)k * 128);
        float a0 = smA[r0 * 132 + k];
        float a1 = smA[r0 * 132 + 132 + k];
        g0[0] = fmaf(a0, wg4.x, g0[0]); g0[1] = fmaf(a0, wg4.y, g0[1]);
        g0[2] = fmaf(a0, wg4.z, g0[2]); g0[3] = fmaf(a0, wg4.w, g0[3]);
        g1[0] = fmaf(a1, wg4.x, g1[0]); g1[1] = fmaf(a1, wg4.y, g1[1]);
        g1[2] = fmaf(a1, wg4.z, g1[2]); g1[3] = fmaf(a1, wg4.w, g1[3]);
        b0[0] = fmaf(a0, wb4.x, b0[0]); b0[1] = fmaf(a0, wb4.y, b0[1]);
        b0[2] = fmaf(a0, wb4.z, b0[2]); b0[3] = fmaf(a0, wb4.w, b0[3]);
        b1[0] = fmaf(a1, wb4.x, b1[0]); b1[1] = fmaf(a1, wb4.y, b1[1]);
        b1[2] = fmaf(a1, wb4.z, b1[2]); b1[3] = fmaf(a1, wb4.w, b1[3]);
    }
    {
        float4 bg4 = *(const float4*)&bg[cq];
        float4 ln0 = *(const float4*)&P.ln_a[(size_t)(row0 + r0) * 128 + cq];
        float4 ln1 = *(const float4*)&P.ln_a[(size_t)(row0 + r0 + 1) * 128 + cq];
        float4 xo0, xo1;
        xo0.x = sig(g0[0] + bg4.x) * ln0.x + b0[0];
        xo0.y = sig(g0[1] + bg4.y) * ln0.y + b0[1];
        xo0.z = sig(g0[2] + bg4.z) * ln0.z + b0[2];
        xo0.w = sig(g0[3] + bg4.w) * ln0.w + b0[3];
        xo1.x = sig(g1[0] + bg4.x) * ln1.x + b1[0];
        xo1.y = sig(g1[1] + bg4.y) * ln1.y + b1[1];
        xo1.z = sig(g1[2] + bg4.z) * ln1.z + b1[2];
        xo1.w = sig(g1[3] + bg4.w) * ln1.w + b1[3];
        *(float4*)&smX[r0 * 132 + cq] = xo0;
        *(float4*)&smX[r0 * 132 + 132 + cq] = xo1;
    }
    __syncthreads();
    // GEMM2: two weight matrices from x/y tile
    const float* W1; const float* W2; int ws2;
    if (u == 0)      { W1 = P.wq + (size_t)i * 16384; W2 = P.wk + (size_t)i * 16384; ws2 = 128; }
    else if (u == 1) { W1 = P.wv + (size_t)i * 16384; W2 = P.wg + (size_t)i * 16384; ws2 = 128; }
    else             { int ch = (u - 2) * 128;
                       W1 = P.ff1 + (size_t)i * 32768 + ch; W2 = P.ff2 + (size_t)i * 32768 + ch; ws2 = 256; }
    W1 += cq; W2 += cq;
    float c10[4] = {}, c11[4] = {}, c20[4] = {}, c21[4] = {};
#pragma unroll 4
    for (int k = 0; k < 128; k++) {
        float4 w14 = *(const float4*)(W1 + (size_t)k * ws2);
        float4 w24 = *(const float4*)(W2 + (size_t)k * ws2);
        float a0 = smX[r0 * 132 + k];
        float a1 = smX[r0 * 132 + 132 + k];
        c10[0] = fmaf(a0, w14.x, c10[0]); c10[1] = fmaf(a0, w14.y, c10[1]);
        c10[2] = fmaf(a0, w14.z, c10[2]); c10[3] = fmaf(a0, w14.w, c10[3]);
        c11[0] = fmaf(a1, w14.x, c11[0]); c11[1] = fmaf(a1, w14.y, c11[1]);
        c11[2] = fmaf(a1, w14.z, c11[2]); c11[3] = fmaf(a1, w14.w, c11[3]);
        c20[0] = fmaf(a0, w24.x, c20[0]); c20[1] = fmaf(a0, w24.y, c20[1]);
        c20[2] = fmaf(a0, w24.z, c20[2]); c20[3] = fmaf(a0, w24.w, c20[3]);
        c21[0] = fmaf(a1, w24.x, c21[0]); c21[1] = fmaf(a1, w24.y, c21[1]);
        c21[2] = fmaf(a1, w24.z, c21[2]); c21[3] = fmaf(a1, w24.w, c21[3]);
    }
    int rA = row0 + r0, rB = row0 + r0 + 1;
    if (u < 2) {
        int obase = u * 256;
        float4 bq4 = make_float4(0, 0, 0, 0);
        if (u == 0) bq4 = *(const float4*)&P.bq[(size_t)i * 128 + cq];
        *(float4*)&P.qkvg[(size_t)rA * 512 + obase + cq] =
            make_float4(c10[0] + bq4.x, c10[1] + bq4.y, c10[2] + bq4.z, c10[3] + bq4.w);
        *(float4*)&P.qkvg[(size_t)rB * 512 + obase + cq] =
            make_float4(c11[0] + bq4.x, c11[1] + bq4.y, c11[2] + bq4.z, c11[3] + bq4.w);
        *(float4*)&P.qkvg[(size_t)rA * 512 + obase + 128 + cq] = make_float4(c20[0], c20[1], c20[2], c20[3]);
        *(float4*)&P.qkvg[(size_t)rB * 512 + obase + 128 + cq] = make_float4(c21[0], c21[1], c21[2], c21[3]);
    } else {
        int ch = (u - 2) * 128;
        float4 oA, oB;
        oA.x = c10[0] * sig(c10[0]) * c20[0]; oA.y = c10[1] * sig(c10[1]) * c20[1];
        oA.z = c10[2] * sig(c10[2]) * c20[2]; oA.w = c10[3] * sig(c10[3]) * c20[3];
        oB.x = c11[0] * sig(c11[0]) * c21[0]; oB.y = c11[1] * sig(c11[1]) * c21[1];
        oB.z = c11[2] * sig(c11[2]) * c21[2]; oB.w = c11[3] * sig(c11[3]) * c21[3];
        *(float4*)&P.ffb[(size_t)rA * 256 + ch + cq] = oA;
        *(float4*)&P.ffb[(size_t)rB * 256 + ch + cq] = oB;
    }
}

// ================= k2: local attention =================
// grid 384 = 8 XCD x 12 j x 4 heads
__global__ __launch_bounds__(256) void k2_attn(Params P, int i)
{
    __shared__ __align__(16) float ks[128 * 36];
    __shared__ __align__(16) float vs[128 * 36];
    __shared__ float ps[32 * PSS];
    int tid = threadIdx.x, bid = blockIdx.x;
    int x8 = bid & 7, g = bid >> 3;
    int h = g / 12, jl = g % 12;
    int j = x8 * 12 + jl;
    int q0 = j * 32;
    int kstart = max(0, q0 - 48);
    int W = min(NTOK, q0 + 80) - kstart;
    // stage K/V
    for (int idx = tid; idx < W * 8; idx += 256) {
        int kk = idx >> 3, d = (idx & 7) * 4;
        const float* base = &P.qkvg[(size_t)(kstart + kk) * 512 + 128 + h * 32 + d];
        float4 tK = *(const float4*)base;
        float4 tV = *(const float4*)(base + 128);
        *(float4*)&ks[kk * 36 + d] = tK;
        *(float4*)&vs[kk * 36 + d] = tV;
    }
    // stage zb tile into ps
    const float* zbase = &P.zb[((size_t)(i * 4 + h) * NTOK + q0) * 128];
#pragma unroll
    for (int it = 0; it < 4; it++) {
        int idx = tid + it * 256;
        int r = idx >> 5, c4 = (idx & 31) * 4;
        float4 z4 = *(const float4*)&zbase[(size_t)r * 128 + c4];
        ps[r * PSS + c4]     = z4.x;
        ps[r * PSS + c4 + 1] = z4.y;
        ps[r * PSS + c4 + 2] = z4.z;
        ps[r * PSS + c4 + 3] = z4.w;
    }
    int qi = tid & 31, kg = tid >> 5;
    float qreg[32];
    {
        const float* qp = &P.qkvg[(size_t)(q0 + qi) * 512 + h * 32];
#pragma unroll
        for (int d4 = 0; d4 < 8; d4++) {
            float4 tq = *(const float4*)(qp + d4 * 4);
            qreg[d4 * 4] = tq.x; qreg[d4 * 4 + 1] = tq.y;
            qreg[d4 * 4 + 2] = tq.z; qreg[d4 * 4 + 3] = tq.w;
        }
    }
    __syncthreads();
    const float scale = 0.17677669529663687f;  // 1/sqrt(32)
#pragma unroll
    for (int t2 = 0; t2 < 16; t2++) {
        int kk = kg + t2 * 8;
        if (kk < W) {
            float acc = 0.0f;
#pragma unroll
            for (int d4 = 0; d4 < 8; d4++) {
                float4 kv = *(const float4*)&ks[kk * 36 + d4 * 4];
                acc = fmaf(qreg[d4 * 4 + 0], kv.x, acc);
                acc = fmaf(qreg[d4 * 4 + 1], kv.y, acc);
                acc = fmaf(qreg[d4 * 4 + 2], kv.z, acc);
                acc = fmaf(qreg[d4 * 4 + 3], kv.w, acc);
            }
            ps[qi * PSS + kk] = fmaf(acc, scale, ps[qi * PSS + kk]);
        }
    }
    __syncthreads();
    {
        int row = tid >> 3, sub = tid & 7;
        float m = -3.0e38f;
        for (int kk = sub; kk < W; kk += 8) m = fmaxf(m, ps[row * PSS + kk]);
#pragma unroll
        for (int s2 = 1; s2 < 8; s2 <<= 1) m = fmaxf(m, __shfl_xor(m, s2));
        float ssum = 0.0f;
        for (int kk = sub; kk < W; kk += 8) {
            float e = expf(ps[row * PSS + kk] - m);
            ps[row * PSS + kk] = e; ssum += e;
        }
#pragma unroll
        for (int s2 = 1; s2 < 8; s2 <<= 1) ssum += __shfl_xor(ssum, s2);
        float rinv = 1.0f / ssum;
        for (int kk = sub; kk < W; kk += 8) ps[row * PSS + kk] *= rinv;
    }
    __syncthreads();
    {
        int dg = tid >> 5, d0 = dg * 4;
        float o0 = 0, o1 = 0, o2 = 0, o3 = 0;
#pragma unroll 2
        for (int kk = 0; kk < W; kk++) {
            float pv = ps[qi * PSS + kk];
            float4 v4 = *(const float4*)&vs[kk * 36 + d0];
            o0 = fmaf(pv, v4.x, o0);
            o1 = fmaf(pv, v4.y, o1);
            o2 = fmaf(pv, v4.z, o2);
            o3 = fmaf(pv, v4.w, o3);
        }
        float4 g4 = *(const float4*)&P.qkvg[(size_t)(q0 + qi) * 512 + 384 + h * 32 + d0];
        float4 r;
        r.x = o0 * sig(g4.x); r.y = o1 * sig(g4.y);
        r.z = o2 * sig(g4.z); r.w = o3 * sig(g4.w);
        *(float4*)&P.attn[(size_t)(q0 + qi) * 128 + h * 32 + d0] = r;
    }
}

// ================= k3: post (sg/wo/sg2/ff3 + next LN or output) =================
// grid 384 = 8 XCD x 48 tiles(8 rows)
__global__ __launch_bounds__(256) void k3_post(Params P, int i)
{
    __shared__ __align__(16) float smA[8 * 132];   // s_ln
    __shared__ __align__(16) float smB[8 * 132];   // attn
    __shared__ __align__(16) float smC[8 * 260];   // ffb
    int tid = threadIdx.x, bid = blockIdx.x;
    int x8 = bid & 7, g = bid >> 3;
    int row0 = (x8 * 48 + g) * 8;
    int lane = tid & 63, wid = tid >> 6;
    int cq = (lane & 31) * 4;
    int r1 = wid * 2 + (lane >> 5);
    {
        int fo = tid * 4;
        int r = fo >> 7, c = fo & 127;
        *(float4*)&smA[r * 132 + c] = *(const float4*)&P.s_ln[(size_t)(row0 + r) * 128 + c];
        *(float4*)&smB[r * 132 + c] = *(const float4*)&P.attn[(size_t)(row0 + r) * 128 + c];
    }
#pragma unroll
    for (int it = 0; it < 2; it++) {
        int fo = (tid + it * 256) * 4;
        int r = fo >> 8, c = fo & 255;
        *(float4*)&smC[r * 260 + c] = *(const float4*)&P.ffb[(size_t)(row0 + r) * 256 + c];
    }
    __syncthreads();
    const float* sgw  = P.sg_w  + (size_t)i * 16384 + cq;
    const float* sg2w = P.sg2_w + (size_t)i * 16384 + cq;
    const float* wo_i = P.wo    + (size_t)i * 16384 + cq;
    const float* f3   = P.ff3   + (size_t)i * 32768 + cq;
    float aG[4] = {}, aG2[4] = {}, aO[4] = {}, aT[4] = {};
#pragma unroll 4
    for (int k = 0; k < 128; k++) {
        float4 w1 = *(const float4*)(sgw  + (size_t)k * 128);
        float4 w2 = *(const float4*)(sg2w + (size_t)k * 128);
        float4 w3 = *(const float4*)(wo_i + (size_t)k * 128);
        float as = smA[r1 * 132 + k];
        float aa = smB[r1 * 132 + k];
        aG[0]  = fmaf(as, w1.x, aG[0]);  aG[1]  = fmaf(as, w1.y, aG[1]);
        aG[2]  = fmaf(as, w1.z, aG[2]);  aG[3]  = fmaf(as, w1.w, aG[3]);
        aG2[0] = fmaf(as, w2.x, aG2[0]); aG2[1] = fmaf(as, w2.y, aG2[1]);
        aG2[2] = fmaf(as, w2.z, aG2[2]); aG2[3] = fmaf(as, w2.w, aG2[3]);
        aO[0]  = fmaf(aa, w3.x, aO[0]);  aO[1]  = fmaf(aa, w3.y, aO[1]);
        aO[2]  = fmaf(aa, w3.z, aO[2]);  aO[3]  = fmaf(aa, w3.w, aO[3]);
    }
#pragma unroll 4
    for (int k = 0; k < 256; k++) {
        float4 w4 = *(const float4*)(f3 + (size_t)k * 128);
        float ac = smC[r1 * 260 + k];
        aT[0] = fmaf(ac, w4.x, aT[0]); aT[1] = fmaf(ac, w4.y, aT[1]);
        aT[2] = fmaf(ac, w4.z, aT[2]); aT[3] = fmaf(ac, w4.w, aT[3]);
    }
    float4 bv  = *(const float4*)&P.sg_b [(size_t)i * 128 + cq];
    float4 bv2 = *(const float4*)&P.sg2_b[(size_t)i * 128 + cq];
    float o0 = sig(aG[0] + bv.x)  * aO[0] + sig(aG2[0] + bv2.x) * aT[0];
    float o1 = sig(aG[1] + bv.y)  * aO[1] + sig(aG2[1] + bv2.y) * aT[1];
    float o2 = sig(aG[2] + bv.z)  * aO[2] + sig(aG2[2] + bv2.z) * aT[2];
    float o3 = sig(aG[3] + bv.w)  * aO[3] + sig(aG2[3] + bv2.w) * aT[3];
    int row = row0 + r1;
    if (i == NBLK - 1) {
        *(float4*)&P.out[(size_t)row * 128 + cq] = make_float4(o0, o1, o2, o3);
    } else {
        // fused LN across the row (cols live in a 32-lane subgroup, 4 each)
        float s = o0 + o1 + o2 + o3;
#pragma unroll
        for (int m = 1; m < 32; m <<= 1) s += __shfl_xor(s, m);
        float mean = s * (1.0f / 128.0f);
        float d0 = o0 - mean, d1 = o1 - mean, d2 = o2 - mean, d3 = o3 - mean;
        float v = d0 * d0 + d1 * d1 + d2 * d2 + d3 * d3;
#pragma unroll
        for (int m = 1; m < 32; m <<= 1) v += __shfl_xor(v, m);
        float rs = 1.0f / sqrtf(v * (1.0f / 128.0f) + 1e-5f);
        *(float4*)&P.ln_a[(size_t)row * 128 + cq] =
            make_float4(d0 * rs, d1 * rs, d2 * rs, d3 * rs);
    }
}

extern "C" void kernel_launch(void* const* d_in, const int* in_sizes, int n_in,
                              void* d_out, int out_size, void* d_ws, size_t ws_size,
                              hipStream_t stream)
{
    Params P;
    P.ql       = (const float*)d_in[0];
    P.cl       = (const float*)d_in[1];
    P.plm      = (const float*)d_in[2];
    P.ada_g_w  = (const float*)d_in[3];
    P.ada_g_b  = (const float*)d_in[4];
    P.ada_b_w  = (const float*)d_in[5];
    P.wq       = (const float*)d_in[6];
    P.bq       = (const float*)d_in[7];
    P.wk       = (const float*)d_in[8];
    P.wv       = (const float*)d_in[9];
    P.z_ln_g   = (const float*)d_in[10];
    P.z_ln_b   = (const float*)d_in[11];
    P.wz       = (const float*)d_in[12];
    P.wg       = (const float*)d_in[13];
    P.wo       = (const float*)d_in[14];
    P.sg_w     = (const float*)d_in[15];
    P.sg_b     = (const float*)d_in[16];
    P.ada2_g_w = (const float*)d_in[17];
    P.ada2_g_b = (const float*)d_in[18];
    P.ada2_b_w = (const float*)d_in[19];
    P.ff1      = (const float*)d_in[20];
    P.ff2      = (const float*)d_in[21];
    P.ff3      = (const float*)d_in[22];
    P.sg2_w    = (const float*)d_in[23];
    P.sg2_b    = (const float*)d_in[24];

    float* ws = (float*)d_ws;
    const size_t NC = (size_t)NTOK * 128;
    P.s_ln = ws;
    P.ln_a = ws + NC;
    P.attn = ws + 2 * NC;
    P.qkvg = ws + 3 * NC;   // N x 512
    P.ffb  = ws + 7 * NC;   // N x 256
    P.zb   = ws + 9 * NC;   // 3 x 4 x N x 128
    P.out  = (float*)d_out;

    k0_init<<<768, 256, 0, stream>>>(P);
    for (int i = 0; i < NBLK; i++) {
        k1_pre<<<768, 256, 0, stream>>>(P, i);
        k2_attn<<<384, 256, 0, stream>>>(P, i);
        k3_post<<<384, 256, 0, stream>>>(P, i);
    }
}